// Round 4
// baseline (924.650 us; speedup 1.0000x reference)
//
#include <hip/hip_runtime.h>
#include <math.h>

// FastGRNN fused recurrence — v4: v3 + weights PINNED in VGPRs + exp2 fold.
// v3 post-mortem: VGPR_Count=92 proves the compiler rematerialized the
// weight loads (const __restrict__ loads are remat-legal) into the t-loop:
// ~530B/lane/step refetched from L1/L2 + addr VALU = the 2x gap vs audit.
// Fix: asm("" : "+v"(x)) pins each weight element into a VGPR (opaque asm
// cannot be rematerialized). Budget: 132 wt + 16 H + 16 ownc + ~50 temps
// ~ 210 < 256 cap from __launch_bounds__(128,2).
// Also: Ueff/WW pre-scaled by log2e so E=exp2(-c') is a bare v_exp_f32
// (saves the ln2 mul per unit; biases enter via Eg=e^-bg, Eu=e^-2bu as before).
// Structure unchanged from v3 (validated absmax 3e-5):
//   block = 2 waves x 8 rows; lane L holds units (2L,2L+1), L<50;
//   wave w owns k in [50w,50w+50); H broadcast via v_readlane (SGPR operand);
//   waves exchange partial-c via double-buffered LDS, 1 barrier/step;
//   both waves redundantly run gates so H stays wave-local.

#define TSTEPS 99
#define DIN    32
#define DH     100
#define NCLS   6
#define XROW   3168
#define R      8

// workspace float offsets
#define OFF_UE 0         // [100][100] log2e * U1@U2
#define OFF_WW 10000     // [32][100]  log2e * W1@W2
#define OFF_EG 13200     // [100] exp(-bias_gate)
#define OFF_EU 13300     // [100] exp(-2*bias_update)
#define OFF_SZ 13400
#define OFF_SN 13401
#define WSF    13402

#define LOG2E 1.44269504088896340736f

__global__ __launch_bounds__(256) void precomp(
    const float* __restrict__ W1, const float* __restrict__ W2,
    const float* __restrict__ U1, const float* __restrict__ U2,
    const float* __restrict__ bg, const float* __restrict__ bu,
    const float* __restrict__ zeta, const float* __restrict__ nu,
    float* __restrict__ ws)
{
    int idx = blockIdx.x * 256 + threadIdx.x;
    if (idx < 10000) {                       // Ueff[k][j] * log2e
        int k = idx / 100, j = idx % 100;
        float v = 0.f;
        #pragma unroll
        for (int r = 0; r < 25; ++r) v = fmaf(U1[k*25 + r], U2[r*DH + j], v);
        ws[OFF_UE + idx] = v * LOG2E;
    } else if (idx < 13200) {                // WW[i][j] * log2e
        int q = idx - 10000; int i = q / 100, j = q % 100;
        float v = 0.f;
        #pragma unroll
        for (int r = 0; r < 16; ++r) v = fmaf(W1[i*16 + r], W2[r*DH + j], v);
        ws[OFF_WW + q] = v * LOG2E;
    } else if (idx < 13300) {
        ws[idx] = expf(-bg[idx - 13200]);
    } else if (idx < 13400) {
        ws[idx] = expf(-2.f * bu[idx - 13300]);
    } else if (idx == 13400) {
        ws[idx] = 1.f / (1.f + expf(-zeta[0]));
    } else if (idx == 13401) {
        ws[idx] = 1.f / (1.f + expf(-nu[0]));
    }
}

__device__ __forceinline__ float rdl(float v, int lane) {
    return __int_as_float(__builtin_amdgcn_readlane(__float_as_int(v), lane));
}

__global__ __launch_bounds__(128, 2) void fastgrnn_main(
    const float* __restrict__ x, const float* __restrict__ ws,
    const float* __restrict__ FC, const float* __restrict__ FCbias,
    float* __restrict__ out)
{
    __shared__ float2 pbuf[2][2][R][64];     // [parity][writer-wave][row][lane] = 16 KB
    const int tid = threadIdx.x;
    const int w   = __builtin_amdgcn_readfirstlane(tid >> 6);  // wave id, SGPR
    const int L   = tid & 63;
    const bool act = (L < 50);
    const int row0 = blockIdx.x * R;

    // ---- one-time: weight columns for units (2L, 2L+1), our k/i halves ----
    float uex[50], uey[50];
    #pragma unroll
    for (int kk = 0; kk < 50; ++kk) {
        float2 v = make_float2(0.f, 0.f);
        if (act) v = *(const float2*)&ws[OFF_UE + (50*w + kk)*DH + 2*L];
        uex[kk] = v.x; uey[kk] = v.y;
        asm("" : "+v"(uex[kk]), "+v"(uey[kk]));   // pin: no remat into t-loop
    }
    float wwx[16], wwy[16];
    #pragma unroll
    for (int ii = 0; ii < 16; ++ii) {
        float2 v = make_float2(0.f, 0.f);
        if (act) v = *(const float2*)&ws[OFF_WW + (16*w + ii)*DH + 2*L];
        wwx[ii] = v.x; wwy[ii] = v.y;
        asm("" : "+v"(wwx[ii]), "+v"(wwy[ii]));   // pin
    }
    float eg0 = act ? ws[OFF_EG + 2*L]     : 1.f;
    float eg1 = act ? ws[OFF_EG + 2*L + 1] : 1.f;
    float eu0 = act ? ws[OFF_EU + 2*L]     : 1.f;
    float eu1 = act ? ws[OFF_EU + 2*L + 1] : 1.f;
    asm("" : "+v"(eg0), "+v"(eg1), "+v"(eu0), "+v"(eu1));
    const float sz  = ws[OFF_SZ];
    const float sn  = ws[OFF_SN];

    float HA[R], HB[R];          // H[2L], H[2L+1] per row (identical in both waves)
    #pragma unroll
    for (int r = 0; r < R; ++r) { HA[r] = 0.f; HB[r] = 0.f; }
    float2 ownc[R];

    const float* __restrict__ xbase = x + (size_t)row0 * XROW + w * 16;

    for (int t = 0; t < TSTEPS; ++t) {
        const int par = t & 1;
        // ---- phase 1: partial c' over our k-half (regs only), write b64 ----
        #pragma unroll
        for (int r = 0; r < R; ++r) {
            const float* xr = xbase + (size_t)r * XROW + t * DIN;
            const float4 xq0 = ((const float4*)xr)[0];
            const float4 xq1 = ((const float4*)xr)[1];
            const float4 xq2 = ((const float4*)xr)[2];
            const float4 xq3 = ((const float4*)xr)[3];

            float axa = 0.f, aya = 0.f, axb = 0.f, ayb = 0.f;
            #pragma unroll
            for (int m = 0; m < 25; ++m) {
                const int mm = 25*w + m;                 // SGPR lane index
                const float ha = rdl(HA[r], mm);         // H[2mm]
                const float hb = rdl(HB[r], mm);         // H[2mm+1]
                axa = fmaf(ha, uex[2*m],   axa);
                aya = fmaf(ha, uey[2*m],   aya);
                axb = fmaf(hb, uex[2*m+1], axb);
                ayb = fmaf(hb, uey[2*m+1], ayb);
            }
            const float xs[16] = { xq0.x, xq0.y, xq0.z, xq0.w,
                                   xq1.x, xq1.y, xq1.z, xq1.w,
                                   xq2.x, xq2.y, xq2.z, xq2.w,
                                   xq3.x, xq3.y, xq3.z, xq3.w };
            #pragma unroll
            for (int ii = 0; ii < 16; ++ii) {
                axa = fmaf(xs[ii], wwx[ii], axa);
                aya = fmaf(xs[ii], wwy[ii], aya);
            }
            float2 c; c.x = axa + axb; c.y = aya + ayb;
            ownc[r] = c;
            pbuf[par][w][r][L] = c;
        }
        __syncthreads();

        // ---- phase 2: combine halves, gates, update H (redundant per wave) ----
        #pragma unroll
        for (int r = 0; r < R; ++r) {
            const float2 oth = pbuf[par][w ^ 1][r][L];
            const float cx = ownc[r].x + oth.x;          // = c * log2e
            const float cy = ownc[r].y + oth.y;
            {
                const float E = __builtin_amdgcn_exp2f(-cx);
                const float g = __builtin_amdgcn_rcpf(fmaf(E, eg0, 1.f));
                float p = E * E * eu0;
                p = fminf(p, 1e30f);
                const float h = (1.f - p) * __builtin_amdgcn_rcpf(1.f + p);
                HA[r] = fmaf(g, HA[r], fmaf(sn, h, fmaf(-sz, g, sz)));
            }
            {
                const float E = __builtin_amdgcn_exp2f(-cy);
                const float g = __builtin_amdgcn_rcpf(fmaf(E, eg1, 1.f));
                float p = E * E * eu1;
                p = fminf(p, 1e30f);
                const float h = (1.f - p) * __builtin_amdgcn_rcpf(1.f + p);
                HB[r] = fmaf(g, HB[r], fmaf(sn, h, fmaf(-sz, g, sz)));
            }
        }
        // no 2nd barrier: next step writes the other parity buffer; pbuf[par]
        // is only rewritten at t+2, after t+1's barrier.
    }

    // ---- epilogue: score = H@FC + bias (wave 0 only; H identical) ----
    if (w == 0) {
        float fc0[NCLS], fc1[NCLS];
        #pragma unroll
        for (int c = 0; c < NCLS; ++c) {
            fc0[c] = act ? FC[(2*L)     * NCLS + c] : 0.f;
            fc1[c] = act ? FC[(2*L + 1) * NCLS + c] : 0.f;
        }
        #pragma unroll
        for (int r = 0; r < R; ++r) {
            float p[NCLS];
            #pragma unroll
            for (int c = 0; c < NCLS; ++c)
                p[c] = fmaf(HA[r], fc0[c], HB[r] * fc1[c]);
            #pragma unroll
            for (int off = 32; off >= 1; off >>= 1) {
                #pragma unroll
                for (int c = 0; c < NCLS; ++c) p[c] += __shfl_xor(p[c], off);
            }
            if (L == 0) {
                #pragma unroll
                for (int c = 0; c < NCLS; ++c)
                    out[(size_t)(row0 + r) * NCLS + c] = p[c] + FCbias[c];
            }
        }
    }
}

extern "C" void kernel_launch(void* const* d_in, const int* in_sizes, int n_in,
                              void* d_out, int out_size, void* d_ws, size_t ws_size,
                              hipStream_t stream)
{
    const float* x    = (const float*)d_in[0];
    const float* W1   = (const float*)d_in[1];
    const float* W2   = (const float*)d_in[2];
    const float* U1   = (const float*)d_in[3];
    const float* U2   = (const float*)d_in[4];
    const float* bg   = (const float*)d_in[5];
    const float* bu   = (const float*)d_in[6];
    const float* zeta = (const float*)d_in[7];
    const float* nu   = (const float*)d_in[8];
    const float* FC   = (const float*)d_in[9];
    const float* FCb  = (const float*)d_in[10];
    float* ws  = (float*)d_ws;
    float* out = (float*)d_out;

    precomp<<<(WSF + 255) / 256, 256, 0, stream>>>(W1, W2, U1, U2, bg, bu,
                                                   zeta, nu, ws);
    fastgrnn_main<<<8192 / R, 128, 0, stream>>>(x, ws, FC, FCb, out);
}

// Round 5
// 356.020 us; speedup vs baseline: 2.5972x; 2.5972x over previous
//
#include <hip/hip_runtime.h>
#include <math.h>

// FastGRNN fused recurrence — v5: split-bf16 MFMA, weights in VGPRs.
// Per step: c[16 rows][112 units] = Hsplit @ Uesplit + xsplit @ WWsplit via
// mfma_f32_16x16x32_bf16 with 4 hi/lo products (error ~2^-17 per operand;
// predicted absmax ~4e-3 vs 2.75e-2 threshold, scaling v3's measured 3e-5).
// Decomposition: block = 256 thr = 4 waves = 2 rowgroups(16 rows) x 2 j-halves.
// Grid 256 -> 1024 waves = 1 wave/SIMD on all 256 CUs -> VGPR budget 512:
// the wave's 40 B-fragments (160 VGPR) are loaded ONCE and pinned with
// asm VOLATILE (v4 lesson: non-volatile empty asm is pure -> LLVM sinks the
// loads back into the loop; VGPR_Count=92 proved it). Zero per-step weight
// traffic. H exchanged via double-buffered LDS [unit][row] (stride 18 =
// 2-way-free banks for the strided A-reads), ONE barrier/step.
// A-frags: row = lane&15, k = (lane>>4)*8+e (k-permutation consistent
// between A and B cancels); C/D: col = lane&15, row = (lane>>4)*4+reg
// (m89-verified). Gates identical math to v3 (validated absmax 3e-5).

typedef __attribute__((ext_vector_type(8))) short short8_t;
typedef __attribute__((ext_vector_type(4))) float f32x4;

#define TSTEPS 99
#define DIN    32
#define DH     100
#define XROW   3168
#define NCLS   6
#define LOG2E  1.44269504088896340736f

// B-frag pack: F = (jt*5 + kt)*2 + s; kt 0..3 = Ueff k-tiles, kt 4 = WW.
// 7 jt x 5 kt x 2 splits = 70 frags x 64 lanes x 16B.
#define NFRAG  70
#define OFF_EG (NFRAG * 256)     // f32 idx: frags take 70*64*4 = 17920 words
#define OFF_EU (OFF_EG + 128)
#define OFF_SZ (OFF_EU + 128)
#define OFF_SN (OFF_SZ + 1)

__device__ __forceinline__ unsigned cvtpk(float a, float b) {
    unsigned r;
    asm("v_cvt_pk_bf16_f32 %0, %1, %2" : "=v"(r) : "v"(a), "v"(b));
    return r;
}
__device__ __forceinline__ float fbits(unsigned u) { return __int_as_float((int)u); }

union F8 { unsigned u4[4]; short8_t s8; };

__global__ __launch_bounds__(256) void precomp(
    const float* __restrict__ W1, const float* __restrict__ W2,
    const float* __restrict__ U1, const float* __restrict__ U2,
    const float* __restrict__ bg, const float* __restrict__ bu,
    const float* __restrict__ zeta, const float* __restrict__ nu,
    float* __restrict__ ws)
{
    const int i = blockIdx.x * 256 + threadIdx.x;
    if (i < NFRAG * 64 / 2 * 2) {               // 4480 frag-lane jobs
        if (i < NFRAG / 2 * 64) {}              // (fallthrough, single branch below)
    }
    if (i < 2240) {                             // one job per (jt,kt,lane): both splits
        const int lane = i & 63, f = i >> 6;    // f = jt*5 + kt, 0..34
        const int jt = f / 5, kt = f % 5;
        const int u = lane & 15, g4 = lane >> 4;
        const int col = jt * 16 + u;
        float v[8];
        #pragma unroll
        for (int e = 0; e < 8; ++e) {
            float s = 0.f;
            if (col < DH) {
                if (kt < 4) {
                    const int k = kt * 32 + g4 * 8 + e;
                    if (k < DH) {
                        #pragma unroll
                        for (int r = 0; r < 25; ++r)
                            s = fmaf(U1[k * 25 + r], U2[r * DH + col], s);
                    }
                } else {
                    const int k = g4 * 8 + e;   // < 32
                    #pragma unroll
                    for (int r = 0; r < 16; ++r)
                        s = fmaf(W1[k * 16 + r], W2[r * DH + col], s);
                }
            }
            v[e] = s * LOG2E;
        }
        unsigned hi[4], lo[4];
        #pragma unroll
        for (int rr = 0; rr < 4; ++rr) {
            const float a = v[2 * rr], b = v[2 * rr + 1];
            const unsigned ph = cvtpk(a, b);
            hi[rr] = ph;
            lo[rr] = cvtpk(a - fbits(ph << 16), b - fbits(ph & 0xffff0000u));
        }
        uint4* B = (uint4*)ws;
        B[(f * 2 + 0) * 64 + lane] = make_uint4(hi[0], hi[1], hi[2], hi[3]);
        B[(f * 2 + 1) * 64 + lane] = make_uint4(lo[0], lo[1], lo[2], lo[3]);
    } else if (i < 2240 + 128) {
        const int p = i - 2240;
        ws[OFF_EG + p] = (p < DH) ? expf(-bg[p]) : 1.f;
    } else if (i < 2240 + 256) {
        const int p = i - 2240 - 128;
        ws[OFF_EU + p] = (p < DH) ? expf(-2.f * bu[p]) : 1.f;
    } else if (i == 2240 + 256) {
        ws[OFF_SZ] = 1.f / (1.f + expf(-zeta[0]));
    } else if (i == 2240 + 257) {
        ws[OFF_SN] = 1.f / (1.f + expf(-nu[0]));
    }
}

__global__ __launch_bounds__(256, 1) void fastgrnn_main(
    const float* __restrict__ x, const float* __restrict__ ws,
    const float* __restrict__ FC, const float* __restrict__ FCbias,
    float* __restrict__ out)
{
    // H double-buffer per rowgroup: [rg][buf][k-unit 0..127][row 0..15], stride 18
    __shared__ float Hl[2][2][128][18];        // 36.9 KB

    const int tid  = threadIdx.x;
    const int lane = tid & 63;
    const int ww   = __builtin_amdgcn_readfirstlane(tid >> 6);  // 0..3
    const int rg   = ww >> 1;
    const int jhalf = ww & 1;
    const int jbase = jhalf * 4;
    const int jn    = jhalf ? 3 : 4;           // j-tiles owned (7 total)
    const int u  = lane & 15;
    const int g4 = lane >> 4;
    const int rowbase = blockIdx.x * 32 + rg * 16;

    // zero LDS (pads k=112..127 must stay 0 forever; initial H = 0)
    for (int z = tid; z < 2 * 2 * 128 * 18; z += 256) ((float*)Hl)[z] = 0.f;

    // ---- one-time: B fragments into pinned VGPRs ----
    F8 Breg[4][5][2];
    #pragma unroll
    for (int jt = 0; jt < 4; ++jt) {
        if (jt < jn) {
            #pragma unroll
            for (int kt = 0; kt < 5; ++kt) {
                #pragma unroll
                for (int s = 0; s < 2; ++s) {
                    const int F = ((jbase + jt) * 5 + kt) * 2 + s;
                    Breg[jt][kt][s].s8 =
                        *(const short8_t*)((const uint4*)ws + F * 64 + lane);
                    asm volatile("" : "+v"(Breg[jt][kt][s].u4[0]),
                                      "+v"(Breg[jt][kt][s].u4[1]),
                                      "+v"(Breg[jt][kt][s].u4[2]),
                                      "+v"(Breg[jt][kt][s].u4[3]));
                }
            }
        }
    }
    float eg_r[4], eu_r[4];
    #pragma unroll
    for (int jt = 0; jt < 4; ++jt) {
        const int unit = (jbase + jt) * 16 + u;   // <= 127, arrays padded to 128
        eg_r[jt] = ws[OFF_EG + unit];
        eu_r[jt] = ws[OFF_EU + unit];
        asm volatile("" : "+v"(eg_r[jt]), "+v"(eu_r[jt]));
    }
    const float sz = ws[OFF_SZ];
    const float sn = ws[OFF_SN];

    const float* __restrict__ xrow = x + (size_t)(rowbase + u) * XROW;

    const f32x4 zero4 = {0.f, 0.f, 0.f, 0.f};
    f32x4 Hold[4];
    #pragma unroll
    for (int jt = 0; jt < 4; ++jt) Hold[jt] = zero4;

    __syncthreads();

    for (int t = 0; t < TSTEPS; ++t) {
        const int rb = t & 1, wb = rb ^ 1;

        // x A-frags (global, issued early; consumed at kt=4)
        F8 xhi, xlo;
        #pragma unroll
        for (int r = 0; r < 4; ++r) {
            const float2 xv = *(const float2*)(xrow + t * DIN + g4 * 8 + 2 * r);
            const unsigned ph = cvtpk(xv.x, xv.y);
            xhi.u4[r] = ph;
            xlo.u4[r] = cvtpk(xv.x - fbits(ph << 16),
                              xv.y - fbits(ph & 0xffff0000u));
        }

        // U A-frags from LDS H (row = u, k = kt*32 + g4*8 + e)
        F8 ahi[4], alo[4];
        #pragma unroll
        for (int kt = 0; kt < 4; ++kt) {
            #pragma unroll
            for (int r = 0; r < 4; ++r) {
                const int k = kt * 32 + g4 * 8 + 2 * r;
                const float h0 = Hl[rg][rb][k][u];
                const float h1 = Hl[rg][rb][k + 1][u];
                const unsigned ph = cvtpk(h0, h1);
                ahi[kt].u4[r] = ph;
                alo[kt].u4[r] = cvtpk(h0 - fbits(ph << 16),
                                      h1 - fbits(ph & 0xffff0000u));
            }
        }

        f32x4 acc[4];
        #pragma unroll
        for (int jt = 0; jt < 4; ++jt) acc[jt] = zero4;

        #pragma unroll
        for (int kt = 0; kt < 5; ++kt) {
            const short8_t Ah = (kt < 4) ? ahi[kt].s8 : xhi.s8;
            const short8_t Al = (kt < 4) ? alo[kt].s8 : xlo.s8;
            // smallest products first; round-robin over jt for ILP
            #pragma unroll
            for (int jt = 0; jt < 4; ++jt)
                if (jt < jn)
                    acc[jt] = __builtin_amdgcn_mfma_f32_16x16x32_bf16(
                        Al, Breg[jt][kt][1].s8, acc[jt], 0, 0, 0);
            #pragma unroll
            for (int jt = 0; jt < 4; ++jt)
                if (jt < jn)
                    acc[jt] = __builtin_amdgcn_mfma_f32_16x16x32_bf16(
                        Al, Breg[jt][kt][0].s8, acc[jt], 0, 0, 0);
            #pragma unroll
            for (int jt = 0; jt < 4; ++jt)
                if (jt < jn)
                    acc[jt] = __builtin_amdgcn_mfma_f32_16x16x32_bf16(
                        Ah, Breg[jt][kt][1].s8, acc[jt], 0, 0, 0);
            #pragma unroll
            for (int jt = 0; jt < 4; ++jt)
                if (jt < jn)
                    acc[jt] = __builtin_amdgcn_mfma_f32_16x16x32_bf16(
                        Ah, Breg[jt][kt][0].s8, acc[jt], 0, 0, 0);
        }

        // gates + H update + write (own j-tiles only)
        #pragma unroll
        for (int jt = 0; jt < 4; ++jt) {
            if (jt < jn) {
                f32x4 hn;
                #pragma unroll
                for (int i = 0; i < 4; ++i) {
                    const float cc = acc[jt][i];               // = c * log2e
                    const float E  = __builtin_amdgcn_exp2f(-cc);
                    const float g  = __builtin_amdgcn_rcpf(fmaf(E, eg_r[jt], 1.f));
                    float p = E * E * eu_r[jt];
                    p = fminf(p, 1e30f);
                    const float h = (1.f - p) * __builtin_amdgcn_rcpf(1.f + p);
                    hn[i] = fmaf(g, Hold[jt][i], fmaf(sn, h, fmaf(-sz, g, sz)));
                }
                Hold[jt] = hn;
                const int unit = (jbase + jt) * 16 + u;
                float* dst = &Hl[rg][wb][unit][g4 * 4];
                *(float2*)(dst)     = make_float2(hn[0], hn[1]);
                *(float2*)(dst + 2) = make_float2(hn[2], hn[3]);
            }
        }
        __syncthreads();
    }

    // ---- epilogue: score = H@FC + bias ----
    const int fb = TSTEPS & 1;   // final H buffer
    if (tid < 192) {
        const int rl = tid / NCLS, c = tid % NCLS;
        const int erg = rl >> 4, row = rl & 15;
        float s = FCbias[c];
        for (int k = 0; k < DH; ++k)
            s = fmaf(Hl[erg][fb][k][row], FC[k * NCLS + c], s);
        out[(size_t)(blockIdx.x * 32 + rl) * NCLS + c] = s;
    }
}

extern "C" void kernel_launch(void* const* d_in, const int* in_sizes, int n_in,
                              void* d_out, int out_size, void* d_ws, size_t ws_size,
                              hipStream_t stream)
{
    const float* x    = (const float*)d_in[0];
    const float* W1   = (const float*)d_in[1];
    const float* W2   = (const float*)d_in[2];
    const float* U1   = (const float*)d_in[3];
    const float* U2   = (const float*)d_in[4];
    const float* bg   = (const float*)d_in[5];
    const float* bu   = (const float*)d_in[6];
    const float* zeta = (const float*)d_in[7];
    const float* nu   = (const float*)d_in[8];
    const float* FC   = (const float*)d_in[9];
    const float* FCb  = (const float*)d_in[10];
    float* ws  = (float*)d_ws;
    float* out = (float*)d_out;

    precomp<<<(2240 + 258 + 255) / 256, 256, 0, stream>>>(
        W1, W2, U1, U2, bg, bu, zeta, nu, ws);
    fastgrnn_main<<<256, 256, 0, stream>>>(x, ws, FC, FCb, out);
}

// Round 9
// 311.081 us; speedup vs baseline: 2.9724x; 1.1445x over previous
//
#include <hip/hip_runtime.h>
#include <math.h>

// FastGRNN fused recurrence — v6: v5 + occupancy fix + ll-product drop.
// (3rd resubmission: rounds 6-8 died on container infra; kernel never ran.)
// v5 post-mortem: VGPR=128 + 160 AGPR (pinned B) = 288 > 256 -> 1 wave/SIMD
// (Occupancy 11.4%); every step's chain fully latency-exposed (Mfma 20%,
// VALU 30%). v6: block = 16 rows x 4 waves, j-tiles split (2,2,2,1) ->
// per-wave B-frags 80 regs, combined ~208 < 256 -> 2 waves/SIMD; grid 512
// -> 2 blocks/CU so one block issues while the other stalls/barriers.
// Numerics: hi/lo split keeps hh+hl+lh, drops ll (residual*residual ~2^-18
// rel — negligible vs v5's measured 3.9e-3 absmax; threshold 2.75e-2).
// H in LDS [buf][row][unit] stride 132: A-frags via 2x ds_read_b128 per kt
// (was 8x b32), banks <=2-way (free). One barrier/step, as before.
// A/B fragment k-mapping constructed identically on both sides (v5-validated).

typedef __attribute__((ext_vector_type(8))) short short8_t;
typedef __attribute__((ext_vector_type(4))) float f32x4;

#define TSTEPS 99
#define DIN    32
#define DH     100
#define XROW   3168
#define NCLS   6
#define LOG2E  1.44269504088896340736f

// B-frag pack in ws: F = (jt*5 + kt)*2 + s; kt 0..3 = Ueff k-tiles, kt 4 = WW.
#define NFRAG  70
#define OFF_EG (NFRAG * 256)
#define OFF_EU (OFF_EG + 128)
#define OFF_SZ (OFF_EU + 128)
#define OFF_SN (OFF_SZ + 1)

__device__ __forceinline__ unsigned cvtpk(float a, float b) {
    unsigned r;
    asm("v_cvt_pk_bf16_f32 %0, %1, %2" : "=v"(r) : "v"(a), "v"(b));
    return r;
}
__device__ __forceinline__ float fbits(unsigned u) { return __int_as_float((int)u); }

union F8 { unsigned u4[4]; short8_t s8; };

__global__ __launch_bounds__(256) void precomp(
    const float* __restrict__ W1, const float* __restrict__ W2,
    const float* __restrict__ U1, const float* __restrict__ U2,
    const float* __restrict__ bg, const float* __restrict__ bu,
    const float* __restrict__ zeta, const float* __restrict__ nu,
    float* __restrict__ ws)
{
    const int i = blockIdx.x * 256 + threadIdx.x;
    if (i < 2240) {                             // one job per (jt,kt,lane)
        const int lane = i & 63, f = i >> 6;    // f = jt*5 + kt, 0..34
        const int jt = f / 5, kt = f % 5;
        const int u = lane & 15, g4 = lane >> 4;
        const int col = jt * 16 + u;
        float v[8];
        #pragma unroll
        for (int e = 0; e < 8; ++e) {
            float s = 0.f;
            if (col < DH) {
                if (kt < 4) {
                    const int k = kt * 32 + g4 * 8 + e;
                    if (k < DH) {
                        #pragma unroll
                        for (int r = 0; r < 25; ++r)
                            s = fmaf(U1[k * 25 + r], U2[r * DH + col], s);
                    }
                } else {
                    const int k = g4 * 8 + e;   // < 32
                    #pragma unroll
                    for (int r = 0; r < 16; ++r)
                        s = fmaf(W1[k * 16 + r], W2[r * DH + col], s);
                }
            }
            v[e] = s * LOG2E;
        }
        unsigned hi[4], lo[4];
        #pragma unroll
        for (int rr = 0; rr < 4; ++rr) {
            const float a = v[2 * rr], b = v[2 * rr + 1];
            const unsigned ph = cvtpk(a, b);
            hi[rr] = ph;
            lo[rr] = cvtpk(a - fbits(ph << 16), b - fbits(ph & 0xffff0000u));
        }
        uint4* B = (uint4*)ws;
        B[(f * 2 + 0) * 64 + lane] = make_uint4(hi[0], hi[1], hi[2], hi[3]);
        B[(f * 2 + 1) * 64 + lane] = make_uint4(lo[0], lo[1], lo[2], lo[3]);
    } else if (i < 2240 + 128) {
        const int p = i - 2240;
        ws[OFF_EG + p] = (p < DH) ? expf(-bg[p]) : 1.f;
    } else if (i < 2240 + 256) {
        const int p = i - 2240 - 128;
        ws[OFF_EU + p] = (p < DH) ? expf(-2.f * bu[p]) : 1.f;
    } else if (i == 2240 + 256) {
        ws[OFF_SZ] = 1.f / (1.f + expf(-zeta[0]));
    } else if (i == 2240 + 257) {
        ws[OFF_SN] = 1.f / (1.f + expf(-nu[0]));
    }
}

__global__ __launch_bounds__(256, 2) void fastgrnn_main(
    const float* __restrict__ x, const float* __restrict__ ws,
    const float* __restrict__ FC, const float* __restrict__ FCbias,
    float* __restrict__ out)
{
    // H double-buffer: [buf][row 0..15][unit 0..131]; stride 132 (16B-aligned
    // rows, b128 reads <=2-way banked). 16.9 KB -> two blocks fit easily.
    __shared__ __align__(16) float Hl[2][16][132];

    const int tid  = threadIdx.x;
    const int lane = tid & 63;
    const int ww   = __builtin_amdgcn_readfirstlane(tid >> 6);  // 0..3
    const int jn   = (ww == 3) ? 1 : 2;        // j-tiles owned: (2,2,2,1)
    const int u    = lane & 15;
    const int g4   = lane >> 4;
    const int rowbase = blockIdx.x * 16;

    // zero both buffers (pad units >=100 must start 0; kt=3 reads k up to 127;
    // B rows k>=100 are zero so any later pad-H garbage is annihilated)
    for (int z = tid; z < 2 * 16 * 132; z += 256) ((float*)Hl)[z] = 0.f;

    // ---- one-time: B fragments into pinned regs (VGPR/AGPR) ----
    F8 Breg[2][5][2];
    #pragma unroll
    for (int jj = 0; jj < 2; ++jj) {
        const int jt = (2 * ww + jj > 6) ? 6 : 2 * ww + jj;  // wave3 dups jt6
        #pragma unroll
        for (int kt = 0; kt < 5; ++kt) {
            #pragma unroll
            for (int s = 0; s < 2; ++s) {
                const int F = (jt * 5 + kt) * 2 + s;
                Breg[jj][kt][s].s8 =
                    *(const short8_t*)((const uint4*)ws + F * 64 + lane);
                asm volatile("" : "+v"(Breg[jj][kt][s].u4[0]),
                                  "+v"(Breg[jj][kt][s].u4[1]),
                                  "+v"(Breg[jj][kt][s].u4[2]),
                                  "+v"(Breg[jj][kt][s].u4[3]));
            }
        }
    }
    float eg_r[2], eu_r[2];
    #pragma unroll
    for (int jj = 0; jj < 2; ++jj) {
        const int jt = (2 * ww + jj > 6) ? 6 : 2 * ww + jj;
        const int unit = jt * 16 + u;          // <=127, arrays padded to 128
        eg_r[jj] = ws[OFF_EG + unit];
        eu_r[jj] = ws[OFF_EU + unit];
        asm volatile("" : "+v"(eg_r[jj]), "+v"(eu_r[jj]));
    }
    const float sz = ws[OFF_SZ];
    const float sn = ws[OFF_SN];

    const float* __restrict__ xrow = x + (size_t)(rowbase + u) * XROW + g4 * 8;

    const f32x4 zero4 = {0.f, 0.f, 0.f, 0.f};
    f32x4 Hold[2];
    Hold[0] = zero4; Hold[1] = zero4;

    __syncthreads();

    for (int t = 0; t < TSTEPS; ++t) {
        const int rb = t & 1, wb = rb ^ 1;

        // x A-frags (2x b128 global; L1-shared across the block's waves)
        F8 xhi, xlo;
        {
            const f32x4 xa = *(const f32x4*)(xrow + t * DIN);
            const f32x4 xb = *(const f32x4*)(xrow + t * DIN + 4);
            const float xs[8] = { xa.x, xa.y, xa.z, xa.w, xb.x, xb.y, xb.z, xb.w };
            #pragma unroll
            for (int r = 0; r < 4; ++r) {
                const unsigned ph = cvtpk(xs[2*r], xs[2*r+1]);
                xhi.u4[r] = ph;
                xlo.u4[r] = cvtpk(xs[2*r]   - fbits(ph << 16),
                                  xs[2*r+1] - fbits(ph & 0xffff0000u));
            }
        }

        // H A-frags: 2x ds_read_b128 per kt from row u
        F8 ahi[4], alo[4];
        #pragma unroll
        for (int kt = 0; kt < 4; ++kt) {
            const f32x4 h0 = *(const f32x4*)&Hl[rb][u][kt * 32 + g4 * 8];
            const f32x4 h1 = *(const f32x4*)&Hl[rb][u][kt * 32 + g4 * 8 + 4];
            const float hs[8] = { h0.x, h0.y, h0.z, h0.w, h1.x, h1.y, h1.z, h1.w };
            #pragma unroll
            for (int r = 0; r < 4; ++r) {
                const unsigned ph = cvtpk(hs[2*r], hs[2*r+1]);
                ahi[kt].u4[r] = ph;
                alo[kt].u4[r] = cvtpk(hs[2*r]   - fbits(ph << 16),
                                      hs[2*r+1] - fbits(ph & 0xffff0000u));
            }
        }

        f32x4 acc[2];
        acc[0] = zero4; acc[1] = zero4;

        #pragma unroll
        for (int kt = 0; kt < 5; ++kt) {
            const short8_t Ah = (kt < 4) ? ahi[kt].s8 : xhi.s8;
            const short8_t Al = (kt < 4) ? alo[kt].s8 : xlo.s8;
            // smallest first: lh, hl, then hh (ll dropped, ~2^-18 rel)
            #pragma unroll
            for (int jj = 0; jj < 2; ++jj)
                if (jj < jn)
                    acc[jj] = __builtin_amdgcn_mfma_f32_16x16x32_bf16(
                        Al, Breg[jj][kt][0].s8, acc[jj], 0, 0, 0);
            #pragma unroll
            for (int jj = 0; jj < 2; ++jj)
                if (jj < jn)
                    acc[jj] = __builtin_amdgcn_mfma_f32_16x16x32_bf16(
                        Ah, Breg[jj][kt][1].s8, acc[jj], 0, 0, 0);
            #pragma unroll
            for (int jj = 0; jj < 2; ++jj)
                if (jj < jn)
                    acc[jj] = __builtin_amdgcn_mfma_f32_16x16x32_bf16(
                        Ah, Breg[jj][kt][0].s8, acc[jj], 0, 0, 0);
        }

        // gates + H update + write own units (C/D: col=u -> unit, row=g4*4+i)
        #pragma unroll
        for (int jj = 0; jj < 2; ++jj) {
            if (jj < jn) {
                f32x4 hn;
                #pragma unroll
                for (int i = 0; i < 4; ++i) {
                    const float cc = acc[jj][i];               // = c * log2e
                    const float E  = __builtin_amdgcn_exp2f(-cc);
                    const float g  = __builtin_amdgcn_rcpf(fmaf(E, eg_r[jj], 1.f));
                    float p = E * E * eu_r[jj];
                    p = fminf(p, 1e30f);
                    const float h = (1.f - p) * __builtin_amdgcn_rcpf(1.f + p);
                    hn[i] = fmaf(g, Hold[jj][i], fmaf(sn, h, fmaf(-sz, g, sz)));
                }
                Hold[jj] = hn;
                const int unit = (2 * ww + jj) * 16 + u;
                Hl[wb][g4 * 4 + 0][unit] = hn[0];
                Hl[wb][g4 * 4 + 1][unit] = hn[1];
                Hl[wb][g4 * 4 + 2][unit] = hn[2];
                Hl[wb][g4 * 4 + 3][unit] = hn[3];
            }
        }
        __syncthreads();
    }

    // ---- epilogue: score = H@FC + bias ----
    const int fb = TSTEPS & 1;   // final H buffer
    if (tid < 16 * NCLS) {
        const int rl = tid / NCLS, c = tid % NCLS;
        float s = FCbias[c];
        for (int k = 0; k < DH; ++k)
            s = fmaf(Hl[fb][rl][k], FC[k * NCLS + c], s);
        out[(size_t)(rowbase + rl) * NCLS + c] = s;
    }
}

extern "C" void kernel_launch(void* const* d_in, const int* in_sizes, int n_in,
                              void* d_out, int out_size, void* d_ws, size_t ws_size,
                              hipStream_t stream)
{
    const float* x    = (const float*)d_in[0];
    const float* W1   = (const float*)d_in[1];
    const float* W2   = (const float*)d_in[2];
    const float* U1   = (const float*)d_in[3];
    const float* U2   = (const float*)d_in[4];
    const float* bg   = (const float*)d_in[5];
    const float* bu   = (const float*)d_in[6];
    const float* zeta = (const float*)d_in[7];
    const float* nu   = (const float*)d_in[8];
    const float* FC   = (const float*)d_in[9];
    const float* FCb  = (const float*)d_in[10];
    float* ws  = (float*)d_ws;
    float* out = (float*)d_out;

    precomp<<<(2240 + 258 + 255) / 256, 256, 0, stream>>>(
        W1, W2, U1, U2, bg, bu, zeta, nu, ws);
    fastgrnn_main<<<512, 256, 0, stream>>>(x, ws, FC, FCb, out);
}